// Round 1
// baseline (3812.322 us; speedup 1.0000x reference)
//
#include <hip/hip_runtime.h>

// MultiLoraLinear: out[b,s,o] = sum_i x[b,s,i] * w[aid[b],o,i]
// M=16384 (B*S), N=4096 (OUT), K=4096 (IN), fp32.
// Strategy: fp32 -> (bf16_hi + bf16_lo) split, 3-term MFMA emulation
// (hh + hl + lh), 128x128 tile, BK=64, reg-staged conversion into
// XOR-swizzled LDS, 4 waves x (4x4) 16x16x32 bf16 MFMA frags.

#define IN_DIM   4096
#define OUT_DIM  4096
#define SEQ      2048
#define BM       128
#define BN       128
#define BK       64
#define KSTEPS   (IN_DIM / BK)   // 64

typedef __attribute__((ext_vector_type(8))) short bf16x8;
typedef __attribute__((ext_vector_type(4))) float f32x4;

__device__ __forceinline__ unsigned short f2bf(float f) {
    unsigned u = __float_as_uint(f);
    unsigned r = 0x7FFFu + ((u >> 16) & 1u);
    return (unsigned short)((u + r) >> 16);
}
__device__ __forceinline__ float bf2f(unsigned short h) {
    return __uint_as_float(((unsigned)h) << 16);
}

// swizzled byte offset for element (row, byte-in-row kb); row stride 128B
#define SWZ(row, kb) ((row)*128 + ((kb) ^ (((row)&7) << 4)))

__global__ __launch_bounds__(256, 2)
void mlora_gemm(const float* __restrict__ x, const int* __restrict__ ids,
                const float* __restrict__ w, float* __restrict__ out) {
    __shared__ __align__(16) char sAh[BM * BK * 2];
    __shared__ __align__(16) char sAl[BM * BK * 2];
    __shared__ __align__(16) char sBh[BM * BK * 2];
    __shared__ __align__(16) char sBl[BM * BK * 2];

    // supertile ordering: 16 groups of (8 mt x 32 nt); bid&7 == mt_local
    // aligns with round-robin XCD dispatch -> A-row L2 reuse per XCD.
    const int bid = blockIdx.x;          // 0..4095
    const int g   = bid >> 8;            // 16 supertiles
    const int idx = bid & 255;
    const int mt  = g * 8 + (idx & 7);   // 0..127
    const int nt  = idx >> 3;            // 0..31

    const int aid = ids[mt >> 4];        // 16 m-tiles per batch (2048/128)

    const int t     = threadIdx.x;
    const int srow  = t >> 1;            // staging row 0..127
    const int shalf = t & 1;             // staging half-row

    const float* pa = x + (size_t)(mt * BM + srow) * IN_DIM + shalf * 32;
    const float* pb = w + (size_t)aid * OUT_DIM * (size_t)IN_DIM
                        + (size_t)(nt * BN + srow) * IN_DIM + shalf * 32;

    union Regs { f32x4 v[8]; float f[32]; };
    Regs ra, rb;

    // prefetch K-step 0
    #pragma unroll
    for (int i = 0; i < 8; ++i) {
        ra.v[i] = *(const f32x4*)(pa + i * 4);
        rb.v[i] = *(const f32x4*)(pb + i * 4);
    }

    const int wid  = t >> 6;
    const int lane = t & 63;
    const int wr   = wid >> 1;           // wave row (2x2 waves of 64x64)
    const int wc   = wid & 1;
    const int lr   = lane & 15;          // frag row/col within 16
    const int lg   = lane >> 4;          // k-group 0..3

    f32x4 acc[4][4];
    #pragma unroll
    for (int m = 0; m < 4; ++m)
        #pragma unroll
        for (int n = 0; n < 4; ++n)
            acc[m][n] = {0.f, 0.f, 0.f, 0.f};

    for (int kt = 0; kt < KSTEPS; ++kt) {
        __syncthreads();   // previous iteration's frag reads complete

        // convert fp32 -> bf16 hi/lo and write swizzled LDS
        #pragma unroll
        for (int c = 0; c < 4; ++c) {
            union { bf16x8 v; unsigned short u[8]; } ah_, al_, bh_, bl_;
            #pragma unroll
            for (int j = 0; j < 8; ++j) {
                float fa = ra.f[c * 8 + j];
                unsigned short ha = f2bf(fa);
                ah_.u[j] = ha;
                al_.u[j] = f2bf(fa - bf2f(ha));
                float fb = rb.f[c * 8 + j];
                unsigned short hb = f2bf(fb);
                bh_.u[j] = hb;
                bl_.u[j] = f2bf(fb - bf2f(hb));
            }
            const int kb = shalf * 64 + c * 16;   // byte-in-row, 16B aligned
            *(bf16x8*)(sAh + SWZ(srow, kb)) = ah_.v;
            *(bf16x8*)(sAl + SWZ(srow, kb)) = al_.v;
            *(bf16x8*)(sBh + SWZ(srow, kb)) = bh_.v;
            *(bf16x8*)(sBl + SWZ(srow, kb)) = bl_.v;
        }
        __syncthreads();

        // issue next tile's global loads; latency hides under MFMAs
        if (kt + 1 < KSTEPS) {
            const float* qa = pa + (kt + 1) * BK;
            const float* qb = pb + (kt + 1) * BK;
            #pragma unroll
            for (int i = 0; i < 8; ++i) {
                ra.v[i] = *(const f32x4*)(qa + i * 4);
                rb.v[i] = *(const f32x4*)(qb + i * 4);
            }
        }

        // compute: 2 k-iters x 4m x 4n x 3 terms = 96 MFMAs
        #pragma unroll
        for (int kk = 0; kk < 2; ++kk) {
            const int kb = kk * 64 + lg * 16;
            bf16x8 bh[4], bl[4];
            #pragma unroll
            for (int n = 0; n < 4; ++n) {
                const int br = wc * 64 + n * 16 + lr;
                bh[n] = *(const bf16x8*)(sBh + SWZ(br, kb));
                bl[n] = *(const bf16x8*)(sBl + SWZ(br, kb));
            }
            #pragma unroll
            for (int m = 0; m < 4; ++m) {
                const int ar = wr * 64 + m * 16 + lr;
                bf16x8 ah = *(const bf16x8*)(sAh + SWZ(ar, kb));
                bf16x8 al = *(const bf16x8*)(sAl + SWZ(ar, kb));
                #pragma unroll
                for (int n = 0; n < 4; ++n) {
                    acc[m][n] = __builtin_amdgcn_mfma_f32_16x16x32_bf16(ah, bh[n], acc[m][n], 0, 0, 0);
                    acc[m][n] = __builtin_amdgcn_mfma_f32_16x16x32_bf16(ah, bl[n], acc[m][n], 0, 0, 0);
                    acc[m][n] = __builtin_amdgcn_mfma_f32_16x16x32_bf16(al, bh[n], acc[m][n], 0, 0, 0);
                }
            }
        }
    }

    // epilogue: C/D layout col = lane&15, row = (lane>>4)*4 + j
    #pragma unroll
    for (int m = 0; m < 4; ++m) {
        #pragma unroll
        for (int n = 0; n < 4; ++n) {
            #pragma unroll
            for (int j = 0; j < 4; ++j) {
                const int rg = mt * BM + wr * 64 + m * 16 + lg * 4 + j;
                const int cg = nt * BN + wc * 64 + n * 16 + lr;
                out[(size_t)rg * OUT_DIM + cg] = acc[m][n][j];
            }
        }
    }
}

extern "C" void kernel_launch(void* const* d_in, const int* in_sizes, int n_in,
                              void* d_out, int out_size, void* d_ws, size_t ws_size,
                              hipStream_t stream) {
    const float* x   = (const float*)d_in[0];
    const int*   ids = (const int*)d_in[1];
    const float* w   = (const float*)d_in[2];
    float*       out = (float*)d_out;

    const int grid = (16384 / BM) * (OUT_DIM / BN);  // 128 * 32 = 4096
    mlora_gemm<<<dim3(grid), dim3(256), 0, stream>>>(x, ids, w, out);
}